// Round 6
// baseline (1306.413 us; speedup 1.0000x reference)
//
#include <hip/hip_runtime.h>
#include <hip/hip_bf16.h>

// Problem constants (B=4, S=2048, D_MODEL=1024, H=16, DH=64, RANK=256, NPRIM=16, top_k=4)
#define TOK 8192
#define SEQ 2048
#define CT  32          // scan chunk length
#define NC  64          // chunks per sequence

typedef __attribute__((ext_vector_type(8))) short bf16x8;   // 8 bf16 = 4 VGPRs
typedef __attribute__((ext_vector_type(4))) float f32x4;
typedef unsigned short u16;
typedef unsigned int   u32;

__device__ __forceinline__ u16 f2bf(float f) {
    u32 u = __float_as_uint(f);
    u = (u + 0x7FFFu + ((u >> 16) & 1u)) >> 16;   // RNE
    return (u16)u;
}
__device__ __forceinline__ float b2f(u16 h) { return __uint_as_float(((u32)h) << 16); }
__device__ __forceinline__ float sigf(float z) { return 1.f / (1.f + __expf(-z)); }

// Top-4 of 16 logits + softmax over the kept 4 (== softmax->topk->renorm, exact).
__device__ __forceinline__ void topk4(const float* __restrict__ lg, int* idx, float* wv)
{
    float v[16];
    #pragma unroll
    for (int i = 0; i < 16; i++) v[i] = lg[i];
    bool used[16];
    #pragma unroll
    for (int i = 0; i < 16; i++) used[i] = false;
    float val[4];
    #pragma unroll
    for (int k = 0; k < 4; k++) {
        int bi = 0; float bv = -3.0e38f;
        #pragma unroll
        for (int i = 0; i < 16; i++)
            if (!used[i] && v[i] > bv) { bv = v[i]; bi = i; }
        used[bi] = true; idx[k] = bi; val[k] = bv;
    }
    float e[4], s = 0.f;
    #pragma unroll
    for (int k = 0; k < 4; k++) { e[k] = expf(val[k] - val[0]); s += e[k]; }
    #pragma unroll
    for (int k = 0; k < 4; k++) wv[k] = e[k] / s;
}

// ---------------------------------------------------------------------------
// prep: one dispatch doing three independent jobs, branch by block range.
//   [0, 10240)      : fp32->bf16 casts of x / out_gate_w / out_proj_w
//   [10240, 12288)  : gather selected prims -> gU (w folded), gVT (transposed)
//   [12288, 14336)  : decay pre-activation dec[t][h] = 1/(1+exp(x.dw_h+b_h))
// ---------------------------------------------------------------------------
__global__ __launch_bounds__(256)
void prep(const float* __restrict__ x, const float* __restrict__ ogw,
          const float* __restrict__ opw,
          const float* __restrict__ qU, const float* __restrict__ kU,
          const float* __restrict__ vU,
          const float* __restrict__ qV, const float* __restrict__ kV,
          const float* __restrict__ vV,
          const float* __restrict__ ql, const float* __restrict__ kl,
          const float* __restrict__ vl, const float* __restrict__ gl,
          const float* __restrict__ dw, const float* __restrict__ db,
          u16* __restrict__ xb, u16* __restrict__ ogwb, u16* __restrict__ opwb,
          u16* __restrict__ gU, u16* __restrict__ gVT, float* __restrict__ dec)
{
    const int blk = blockIdx.x;
    const int tid = threadIdx.x;

    if (blk < 10240) {
        // ---- bulk bf16 casts: 2621440 float4-groups ----
        const int i = blk * 256 + tid;
        const float* src; u16* dst; int off;
        if (i < 2097152)      { src = x;   dst = xb;   off = i; }
        else if (i < 2359296) { src = ogw; dst = ogwb; off = i - 2097152; }
        else                  { src = opw; dst = opwb; off = i - 2359296; }
        const float4 v = ((const float4*)src)[off];
        __align__(8) u16 t[4] = { f2bf(v.x), f2bf(v.y), f2bf(v.z), f2bf(v.w) };
        ((uint2*)dst)[off] = *(const uint2*)t;
        return;
    }
    if (blk < 12288) {
        // ---- gather (topk inline, exact) ----
        const int local = blk - 10240;
        const int z = local >> 8;              // 0..7
        const int bx = local & 15, by = (local >> 4) & 15;
        const int p = z & 3;
        const float* lg = (p == 0) ? ql : (p == 1) ? kl : (p == 2) ? vl : gl;
        int idx[4]; float wsel[4];
        topk4(lg, idx, wsel);

        if (z < 4) {
            // V^T gather: gVT[p][o][k=s*256+r] = V_sel[s][r][o]
            const float* V = (p == 0) ? qV : (p == 1) ? kV : vV;
            const int o0 = bx * 64, k0 = by * 64;
            const int s = k0 >> 8, r0 = k0 & 255;
            const float* Vb = V + (size_t)idx[s] * (256 * 1024);
            __shared__ float tile[64][68];
            const int rr = tid >> 4, cc = (tid & 15) << 2;
            #pragma unroll
            for (int i = 0; i < 4; i++) {
                const float4 v = *(const float4*)(Vb + (size_t)(r0 + rr + 16 * i) * 1024 + o0 + cc);
                *(float4*)&tile[rr + 16 * i][cc] = v;
            }
            __syncthreads();
            const int oo = tid >> 4, kk = (tid & 15) << 2;
            u16* out = gVT + (size_t)p * 1048576;
            #pragma unroll
            for (int i = 0; i < 4; i++) {
                __align__(8) u16 t[4];
                #pragma unroll
                for (int j = 0; j < 4; j++) t[j] = f2bf(tile[kk + j][oo + 16 * i]);
                *(uint2*)(out + (size_t)(o0 + oo + 16 * i) * 1024 + k0 + kk) = *(const uint2*)t;
            }
        } else {
            // U gather: gU[p][d][k=s*256+r] = w_s * U_sel[s][d][r]
            const float* U = (p == 0) ? qU : (p == 1) ? kU : vU;
            const int d0 = bx * 64, k0 = by * 64;
            const int s = k0 >> 8, r0 = k0 & 255;
            const float* Ub = U + (size_t)idx[s] * (1024 * 256);
            const float wq = wsel[s];
            u16* out = gU + (size_t)p * 1048576;
            const int rr = tid >> 4, cc = (tid & 15) << 2;
            #pragma unroll
            for (int i = 0; i < 4; i++) {
                const float4 v = *(const float4*)(Ub + (size_t)(d0 + rr + 16 * i) * 256 + r0 + cc);
                __align__(8) u16 t[4] = { f2bf(v.x * wq), f2bf(v.y * wq),
                                          f2bf(v.z * wq), f2bf(v.w * wq) };
                *(uint2*)(out + (size_t)(d0 + rr + 16 * i) * 1024 + k0 + cc) = *(const uint2*)t;
            }
        }
        return;
    }
    // ---- decay: one wave per token ----
    {
        const int tg = blk - 12288;
        const int wave = tid >> 6, lane = tid & 63;
        const int t = tg * 4 + wave;
        const float4* x4 = (const float4*)(x + (size_t)t * 1024);
        float4 xv[4];
        #pragma unroll
        for (int i = 0; i < 4; i++) xv[i] = x4[lane + 64 * i];
        float p[16];
        #pragma unroll
        for (int h = 0; h < 16; h++) {
            const float4* w4 = (const float4*)(dw + (size_t)h * 1024);
            float s = 0.f;
            #pragma unroll
            for (int i = 0; i < 4; i++) {
                const float4 wv = w4[lane + 64 * i];
                s = fmaf(xv[i].x, wv.x, fmaf(xv[i].y, wv.y,
                    fmaf(xv[i].z, wv.z, fmaf(xv[i].w, wv.w, s))));
            }
            p[h] = s;
        }
        #pragma unroll
        for (int off = 32; off > 0; off >>= 1)
            #pragma unroll
            for (int h = 0; h < 16; h++) p[h] += __shfl_xor(p[h], off);
        if (lane == 0) {
            #pragma unroll
            for (int h = 0; h < 16; h++)
                dec[(size_t)t * 16 + h] = 1.f / (1.f + __expf(p[h] + db[h]));
        }
    }
}

// ---------------------------------------------------------------------------
// 64x64-tile bf16 MFMA GEMM for W_eff^T: C[m][n] = sum_k A[m,k]*B[n,k],
// M=N=K=1024, z batches slices of 1M elements. grid (16,16,4) -> 4 blocks/CU.
// ---------------------------------------------------------------------------
__global__ __launch_bounds__(256)
void mfma_gemm64(const u16* __restrict__ Asrc, const u16* __restrict__ Bsrc,
                 u16* __restrict__ Cout)
{
    __shared__ u16 As[64 * 64];
    __shared__ u16 Bs[64 * 64];
    const int z = blockIdx.z;
    const u16* A = Asrc + (size_t)z * 1048576;
    const u16* B = Bsrc + (size_t)z * 1048576;
    u16* C = Cout + (size_t)z * 1048576;
    const int tid = threadIdx.x, lane = tid & 63, wave = tid >> 6;
    const int m0 = blockIdx.y * 64, n0 = blockIdx.x * 64;
    const int wn = wave * 16;

    f32x4 acc[4];
    #pragma unroll
    for (int i = 0; i < 4; i++) acc[i] = (f32x4)0.f;

    for (int k0 = 0; k0 < 1024; k0 += 64) {
        __syncthreads();
        #pragma unroll
        for (int it = 0; it < 2; it++) {
            const int c   = it * 256 + tid;
            const int row = c >> 3, j = c & 7;
            const int g   = j ^ (row & 7);
            const u16* ga = A + (size_t)(m0 + row) * 1024 + k0 + g * 8;
            __builtin_amdgcn_global_load_lds(
                (const __attribute__((address_space(1))) u32*)ga,
                (__attribute__((address_space(3))) u32*)&As[(it * 256 + wave * 64) * 8],
                16, 0, 0);
            const u16* gb = B + (size_t)(n0 + row) * 1024 + k0 + g * 8;
            __builtin_amdgcn_global_load_lds(
                (const __attribute__((address_space(1))) u32*)gb,
                (__attribute__((address_space(3))) u32*)&Bs[(it * 256 + wave * 64) * 8],
                16, 0, 0);
        }
        __syncthreads();
        #pragma unroll
        for (int ks = 0; ks < 2; ks++) {
            const int gk = ks * 4 + (lane >> 4);
            const int rn = wn + (lane & 15);
            const int jb = gk ^ (rn & 7);
            const bf16x8 bfr = *(const bf16x8*)&Bs[rn * 64 + jb * 8];
            #pragma unroll
            for (int mi = 0; mi < 4; mi++) {
                const int rm = mi * 16 + (lane & 15);
                const int ja = gk ^ (rm & 7);
                const bf16x8 af = *(const bf16x8*)&As[rm * 64 + ja * 8];
                acc[mi] = __builtin_amdgcn_mfma_f32_16x16x32_bf16(af, bfr, acc[mi], 0, 0, 0);
            }
        }
    }
    const int col_l = lane & 15, row_l = (lane >> 4) * 4;
    #pragma unroll
    for (int mi = 0; mi < 4; mi++)
        #pragma unroll
        for (int i = 0; i < 4; i++)
            C[(size_t)(m0 + mi * 16 + row_l + i) * 1024 + n0 + wn + col_l] = f2bf(acc[mi][i]);
}

// ---------------------------------------------------------------------------
// 128x128-tile bf16 MFMA GEMM, M=8192, N=K=1024, z-batched. XCD-swizzled
// block decode (flat%8 = XCD under round-robin) pins an 8-row m-group per
// XCD: per-z working set A 2MB + B 2MB fits the 4MB XCD L2.
// REQUIRES grid == (8, 64, Z).
// ---------------------------------------------------------------------------
template<int OUTBF>
__global__ __launch_bounds__(256)
void mfma_gemm(const u16* __restrict__ Asrc, const u16* __restrict__ Bt,
               void* __restrict__ Cout, size_t astride, size_t bstride, size_t cstride)
{
    __shared__ u16 As[128 * 64];
    __shared__ u16 Bs[128 * 64];
    const int flat = blockIdx.x + 8 * (blockIdx.y + 64 * blockIdx.z);
    const int xcd = flat & 7;
    const int r   = flat >> 3;
    const int nb = r & 7, mlocal = (r >> 3) & 7, zb = r >> 6;
    const int m0 = (xcd * 8 + mlocal) * 128, n0 = nb * 128;

    const u16* A = Asrc + (size_t)zb * astride;
    const u16* B = Bt   + (size_t)zb * bstride;
    const int tid  = threadIdx.x;
    const int lane = tid & 63, wave = tid >> 6;
    const int wm = (wave >> 1) * 64, wn = (wave & 1) * 64;

    f32x4 acc[4][4];
    #pragma unroll
    for (int i = 0; i < 4; i++)
        #pragma unroll
        for (int j = 0; j < 4; j++) acc[i][j] = (f32x4)0.f;

    for (int k0 = 0; k0 < 1024; k0 += 64) {
        __syncthreads();
        #pragma unroll
        for (int it = 0; it < 4; it++) {
            const int c   = it * 256 + tid;
            const int row = c >> 3, j = c & 7;
            const int g   = j ^ (row & 7);
            const u16* ga = A + (size_t)(m0 + row) * 1024 + k0 + g * 8;
            __builtin_amdgcn_global_load_lds(
                (const __attribute__((address_space(1))) u32*)ga,
                (__attribute__((address_space(3))) u32*)&As[(it * 256 + wave * 64) * 8],
                16, 0, 0);
            const u16* gb = B + (size_t)(n0 + row) * 1024 + k0 + g * 8;
            __builtin_amdgcn_global_load_lds(
                (const __attribute__((address_space(1))) u32*)gb,
                (__attribute__((address_space(3))) u32*)&Bs[(it * 256 + wave * 64) * 8],
                16, 0, 0);
        }
        __syncthreads();
        #pragma unroll
        for (int ks = 0; ks < 2; ks++) {
            bf16x8 af[4], bfr[4];
            const int gk = ks * 4 + (lane >> 4);
            #pragma unroll
            for (int mi = 0; mi < 4; mi++) {
                const int rr  = wm + mi * 16 + (lane & 15);
                const int ja = gk ^ (rr & 7);
                af[mi] = *(const bf16x8*)&As[rr * 64 + ja * 8];
                const int rn = wn + mi * 16 + (lane & 15);
                const int jb = gk ^ (rn & 7);
                bfr[mi] = *(const bf16x8*)&Bs[rn * 64 + jb * 8];
            }
            #pragma unroll
            for (int mi = 0; mi < 4; mi++)
                #pragma unroll
                for (int ni = 0; ni < 4; ni++)
                    acc[mi][ni] = __builtin_amdgcn_mfma_f32_16x16x32_bf16(
                        af[mi], bfr[ni], acc[mi][ni], 0, 0, 0);
        }
    }
    // epilogue: C/D layout col=lane&15, row=(lane>>4)*4+reg  [m89-verified]
    const int col_l = lane & 15, row_l = (lane >> 4) * 4;
    if (OUTBF) {
        u16* C = (u16*)Cout + (size_t)zb * cstride;
        #pragma unroll
        for (int mi = 0; mi < 4; mi++)
            #pragma unroll
            for (int ni = 0; ni < 4; ni++)
                #pragma unroll
                for (int i = 0; i < 4; i++) {
                    const int rw  = m0 + wm + mi * 16 + row_l + i;
                    const int cn = n0 + wn + ni * 16 + col_l;
                    C[(size_t)rw * 1024 + cn] = f2bf(acc[mi][ni][i]);
                }
    } else {
        float* C = (float*)Cout + (size_t)zb * cstride;
        #pragma unroll
        for (int mi = 0; mi < 4; mi++)
            #pragma unroll
            for (int ni = 0; ni < 4; ni++)
                #pragma unroll
                for (int i = 0; i < 4; i++) {
                    const int rw  = m0 + wm + mi * 16 + row_l + i;
                    const int cn = n0 + wn + ni * 16 + col_l;
                    C[(size_t)rw * 1024 + cn] = acc[mi][ni][i];
                }
    }
}

// ---------------------------------------------------------------------------
// Single-pass chunk scan with decoupled lookback. One wave per (b,h,chunk).
// Phase 1: local scan (kv, a held in VGPRs). Publish aggregate (L[d], P) or
// inclusive state; lookback terminates at first inclusive entry (c=0 is
// inclusive immediately). Phase 2: replay from registers, write att bf16.
// Chunk index in low bits of blockIdx.x -> predecessors dispatch first.
// ---------------------------------------------------------------------------
__global__ __launch_bounds__(64)
void scan_lb(const u16* __restrict__ Qq, const u16* __restrict__ Kq,
             const u16* __restrict__ Vq, const u16* __restrict__ Gq,
             const float* __restrict__ dec,
             float* __restrict__ Lagg, float* __restrict__ Sincl,
             float* __restrict__ Pagg, u32* __restrict__ flags,
             u16* __restrict__ attb)
{
    const int ci = blockIdx.x;
    const int c = ci & (NC - 1), h = (ci >> 6) & 15, b = ci >> 10;
    const int d = threadIdx.x;
    const size_t t0 = (size_t)b * SEQ + c * CT;
    const size_t base = t0 * 1024 + h * 64 + d;
    const float* dp = dec + t0 * 16 + h;

    float kvr[CT], ar[CT];
    float L = 0.f, P = 1.f;
    #pragma unroll
    for (int t = 0; t < CT; t++) {
        const size_t o = (size_t)t * 1024;
        const float a  = dp[t * 16];
        const float kv = b2f(Kq[base + o]) * b2f(Vq[base + o]) * sigf(b2f(Gq[base + o]));
        ar[t] = a; kvr[t] = kv;
        L = fmaf(a, L, kv);
        P *= a;
    }

    float sprev = 0.f;
    if (c == 0) {
        Sincl[(size_t)ci * 64 + d] = L;
        __threadfence();
        if (d == 0) atomicExch(&flags[ci], 2u);
    } else {
        Lagg[(size_t)ci * 64 + d] = L;
        if (d == 0) Pagg[ci] = P;
        __threadfence();
        if (d == 0) atomicExch(&flags[ci], 1u);
        float carry = 1.f;
        int j = ci - 1;
        while (true) {
            u32 f;
            do {
                f = atomicAdd(&flags[j], 0u);
                if (f == 0u) __builtin_amdgcn_s_sleep(1);
            } while (f == 0u);
            __threadfence();   // acquire: invalidate L1 before reading payload
            if (f == 2u) { sprev = fmaf(carry, Sincl[(size_t)j * 64 + d], sprev); break; }
            sprev = fmaf(carry, Lagg[(size_t)j * 64 + d], sprev);
            carry *= Pagg[j];
            j--;
        }
        Sincl[(size_t)ci * 64 + d] = fmaf(P, sprev, L);
        __threadfence();
        if (d == 0) atomicExch(&flags[ci], 2u);
    }

    float s = sprev;
    #pragma unroll
    for (int t = 0; t < CT; t++) {
        const size_t o = (size_t)t * 1024;
        s = fmaf(ar[t], s, kvr[t]);
        attb[base + o] = f2bf(b2f(Qq[base + o]) * s);
    }
}

// ---------------------------------------------------------------------------
// RMSNorm * rms_w * sigmoid(gpre) -> bf16, one block per token (bf16 in)
// ---------------------------------------------------------------------------
__global__ __launch_bounds__(256)
void rms_gate(const u16* __restrict__ attb, const u16* __restrict__ gpre,
              const float* __restrict__ rmsw, u16* __restrict__ o)
{
    const size_t t = blockIdx.x;
    const int tid = threadIdx.x;
    const ushort4 a4 = ((const ushort4*)(attb + t * 1024))[tid];
    const float ax = b2f(a4.x), ay = b2f(a4.y), az = b2f(a4.z), aw = b2f(a4.w);
    float ss = ax*ax + ay*ay + az*az + aw*aw;
    #pragma unroll
    for (int d = 32; d > 0; d >>= 1) ss += __shfl_down(ss, d);
    __shared__ float red[4];
    if ((tid & 63) == 0) red[tid >> 6] = ss;
    __syncthreads();
    const float tot = red[0] + red[1] + red[2] + red[3];
    const float scale = rsqrtf(tot * (1.0f / 1024.0f) + 1.1920929e-7f);
    const ushort4 g4 = ((const ushort4*)(gpre + t * 1024))[tid];
    const float4 w   = ((const float4*)rmsw)[tid];
    __align__(8) u16 r[4];
    r[0] = f2bf(ax * scale * w.x * sigf(b2f(g4.x)));
    r[1] = f2bf(ay * scale * w.y * sigf(b2f(g4.y)));
    r[2] = f2bf(az * scale * w.z * sigf(b2f(g4.z)));
    r[3] = f2bf(aw * scale * w.w * sigf(b2f(g4.w)));
    ((uint2*)(o + t * 1024))[tid] = *(const uint2*)r;
}

// ---------------------------------------------------------------------------
extern "C" void kernel_launch(void* const* d_in, const int* in_sizes, int n_in,
                              void* d_out, int out_size, void* d_ws, size_t ws_size,
                              hipStream_t stream)
{
    const float* x    = (const float*)d_in[0];
    const float* qU   = (const float*)d_in[1];
    const float* qV   = (const float*)d_in[2];
    const float* kU   = (const float*)d_in[3];
    const float* kV   = (const float*)d_in[4];
    const float* vU   = (const float*)d_in[5];
    const float* vV   = (const float*)d_in[6];
    const float* ql   = (const float*)d_in[7];
    const float* kl   = (const float*)d_in[8];
    const float* vl   = (const float*)d_in[9];
    const float* gl   = (const float*)d_in[10];
    const float* dw   = (const float*)d_in[11];
    const float* db   = (const float*)d_in[12];
    const float* ogw  = (const float*)d_in[13];
    const float* opw  = (const float*)d_in[14];
    const float* rmsw = (const float*)d_in[15];

    // workspace layout (byte offsets, ~149.5 MB total)
    char* w = (char*)d_ws;
    float* dec   = (float*)(w + 0);           // 512 KB
    u16*   WT    = (u16*)  (w + 524288);      // 5 slices x 2 MB (slice4 = ogwb)
    u16*   xb    = (u16*)  (w + 11010048);    // 16 MB
    u16*   opwb  = (u16*)  (w + 27787264);    // 2 MB
    u16*   QKVG  = (u16*)  (w + 29884416);    // 5 slices x 16 MB (q,k,v,g,gpre)
    u16*   RMSO  = (u16*)  (w + 113770496);   // 16 MB
    u16*   ATTb  = (u16*)  (w + 130547712);   // 16 MB
    float* Lagg  = (float*)(w + 147324928);   // 1 MB
    float* Sincl = (float*)(w + 148373504);   // 1 MB
    float* Pagg  = (float*)(w + 149422080);   // 16 KB
    u32*   flags = (u32*)  (w + 149438464);   // 16 KB
    // gU/gVT alias the QKVG region (consumed by weff-gemm before QKVG written)
    u16*   gU    = QKVG;                      // 8 MB
    u16*   gVT   = QKVG + 4194304;            // 8 MB
    u16*   ogwb  = WT + 4 * 1048576;          // WT slice 4
    u16*   GPRE  = QKVG + 4 * 8388608;        // QKVG slice 4

    // 0. lookback flags must start at 0 (ws is poisoned 0xAA each call)
    hipMemsetAsync(flags, 0, 4096 * sizeof(u32), stream);

    // 1. prep: casts + prim gathers + decay (independent jobs, one dispatch)
    prep<<<14336, 256, 0, stream>>>(x, ogw, opw, qU, kU, vU, qV, kV, vV,
                                    ql, kl, vl, gl, dw, db,
                                    xb, ogwb, opwb, gU, gVT, dec);

    // 2. WT[p][o][d] = sum_k gVT[p][o,k] * gU[p][d,k]  (= W_eff^T)
    mfma_gemm64<<<dim3(16, 16, 4), 256, 0, stream>>>(gVT, gU, WT);

    // 3. q,k,v,gate,gpre = x @ {W_eff_p, out_gate_w}^T -> bf16, z=5 batch
    mfma_gemm<1><<<dim3(8, 64, 5), 256, 0, stream>>>(xb, WT, QKVG,
                                                     (size_t)0, (size_t)1048576,
                                                     (size_t)8388608);

    // 4. single-pass chunk scan with decoupled lookback
    scan_lb<<<4096, 64, 0, stream>>>(QKVG, QKVG + 8388608, QKVG + 16777216,
                                     QKVG + 25165824, dec,
                                     Lagg, Sincl, Pagg, flags, ATTb);

    // 5. rmsnorm * gate
    rms_gate<<<8192, 256, 0, stream>>>(ATTb, GPRE, rmsw, RMSO);

    // 6. final: rmso @ out_proj_w^T -> fp32 d_out
    mfma_gemm<0><<<dim3(8, 64, 1), 256, 0, stream>>>(RMSO, opwb, (float*)d_out, 0, 0, 0);
}

// Round 7
// 393.987 us; speedup vs baseline: 3.3159x; 3.3159x over previous
//
#include <hip/hip_runtime.h>
#include <hip/hip_bf16.h>

// Problem constants (B=4, S=2048, D_MODEL=1024, H=16, DH=64, RANK=256, NPRIM=16, top_k=4)
#define TOK 8192
#define SEQ 2048
#define CT  32          // scan chunk length
#define NC  64          // chunks per sequence

typedef __attribute__((ext_vector_type(8))) short bf16x8;   // 8 bf16 = 4 VGPRs
typedef __attribute__((ext_vector_type(4))) float f32x4;
typedef unsigned short u16;
typedef unsigned int   u32;

__device__ __forceinline__ u16 f2bf(float f) {
    u32 u = __float_as_uint(f);
    u = (u + 0x7FFFu + ((u >> 16) & 1u)) >> 16;   // RNE
    return (u16)u;
}
__device__ __forceinline__ float b2f(u16 h) { return __uint_as_float(((u32)h) << 16); }
__device__ __forceinline__ float sigf(float z) { return 1.f / (1.f + __expf(-z)); }

// Top-4 of 16 logits + softmax over the kept 4 (== softmax->topk->renorm, exact).
__device__ __forceinline__ void topk4(const float* __restrict__ lg, int* idx, float* wv)
{
    float v[16];
    #pragma unroll
    for (int i = 0; i < 16; i++) v[i] = lg[i];
    bool used[16];
    #pragma unroll
    for (int i = 0; i < 16; i++) used[i] = false;
    float val[4];
    #pragma unroll
    for (int k = 0; k < 4; k++) {
        int bi = 0; float bv = -3.0e38f;
        #pragma unroll
        for (int i = 0; i < 16; i++)
            if (!used[i] && v[i] > bv) { bv = v[i]; bi = i; }
        used[bi] = true; idx[k] = bi; val[k] = bv;
    }
    float e[4], s = 0.f;
    #pragma unroll
    for (int k = 0; k < 4; k++) { e[k] = expf(val[k] - val[0]); s += e[k]; }
    #pragma unroll
    for (int k = 0; k < 4; k++) wv[k] = e[k] / s;
}

// ---------------------------------------------------------------------------
// prep: one dispatch, branch by block range.
//   [0, 2048)    : x cast -> bf16 AND decay dec[t][h] (x row held in regs)
//   [2048, 3072) : out_gate_w cast
//   [3072, 4096) : out_proj_w cast
//   [4096, 6144) : gather selected prims -> gU (w folded), gVT (transposed)
// ---------------------------------------------------------------------------
__global__ __launch_bounds__(256)
void prep(const float* __restrict__ x, const float* __restrict__ ogw,
          const float* __restrict__ opw,
          const float* __restrict__ qU, const float* __restrict__ kU,
          const float* __restrict__ vU,
          const float* __restrict__ qV, const float* __restrict__ kV,
          const float* __restrict__ vV,
          const float* __restrict__ ql, const float* __restrict__ kl,
          const float* __restrict__ vl, const float* __restrict__ gl,
          const float* __restrict__ dw, const float* __restrict__ db,
          u16* __restrict__ xb, u16* __restrict__ ogwb, u16* __restrict__ opwb,
          u16* __restrict__ gU, u16* __restrict__ gVT, float* __restrict__ dec)
{
    const int blk = blockIdx.x;
    const int tid = threadIdx.x;

    if (blk < 2048) {
        // ---- x cast + decay: one wave per token ----
        const int wave = tid >> 6, lane = tid & 63;
        const int t = blk * 4 + wave;
        const float4* x4 = (const float4*)(x + (size_t)t * 1024);
        float4 xv[4];
        #pragma unroll
        for (int i = 0; i < 4; i++) xv[i] = x4[lane + 64 * i];
        // cast-store the row
        uint2* xrow = (uint2*)(xb + (size_t)t * 1024);
        #pragma unroll
        for (int i = 0; i < 4; i++) {
            __align__(8) u16 tq[4] = { f2bf(xv[i].x), f2bf(xv[i].y),
                                       f2bf(xv[i].z), f2bf(xv[i].w) };
            xrow[lane + 64 * i] = *(const uint2*)tq;
        }
        // 16 head dots from the same registers
        float p[16];
        #pragma unroll
        for (int h = 0; h < 16; h++) {
            const float4* w4 = (const float4*)(dw + (size_t)h * 1024);
            float s = 0.f;
            #pragma unroll
            for (int i = 0; i < 4; i++) {
                const float4 wv = w4[lane + 64 * i];
                s = fmaf(xv[i].x, wv.x, fmaf(xv[i].y, wv.y,
                    fmaf(xv[i].z, wv.z, fmaf(xv[i].w, wv.w, s))));
            }
            p[h] = s;
        }
        #pragma unroll
        for (int off = 32; off > 0; off >>= 1)
            #pragma unroll
            for (int h = 0; h < 16; h++) p[h] += __shfl_xor(p[h], off);
        if (lane == 0) {
            #pragma unroll
            for (int h = 0; h < 16; h++)
                dec[(size_t)t * 16 + h] = 1.f / (1.f + __expf(p[h] + db[h]));
        }
        return;
    }
    if (blk < 4096) {
        // ---- weight casts: 1 float4 per thread ----
        const float* src; u16* dst;
        int off;
        if (blk < 3072) { src = ogw; dst = ogwb; off = (blk - 2048) * 256 + tid; }
        else            { src = opw; dst = opwb; off = (blk - 3072) * 256 + tid; }
        const float4 v = ((const float4*)src)[off];
        __align__(8) u16 t[4] = { f2bf(v.x), f2bf(v.y), f2bf(v.z), f2bf(v.w) };
        ((uint2*)dst)[off] = *(const uint2*)t;
        return;
    }
    // ---- gather (topk inline, exact) ----
    {
        const int local = blk - 4096;
        const int z = local >> 8;              // 0..7
        const int bx = local & 15, by = (local >> 4) & 15;
        const int p = z & 3;
        const float* lg = (p == 0) ? ql : (p == 1) ? kl : (p == 2) ? vl : gl;
        int idx[4]; float wsel[4];
        topk4(lg, idx, wsel);

        if (z < 4) {
            // V^T gather: gVT[p][o][k=s*256+r] = V_sel[s][r][o]
            const float* V = (p == 0) ? qV : (p == 1) ? kV : vV;
            const int o0 = bx * 64, k0 = by * 64;
            const int s = k0 >> 8, r0 = k0 & 255;
            const float* Vb = V + (size_t)idx[s] * (256 * 1024);
            __shared__ float tile[64][68];
            const int rr = tid >> 4, cc = (tid & 15) << 2;
            #pragma unroll
            for (int i = 0; i < 4; i++) {
                const float4 v = *(const float4*)(Vb + (size_t)(r0 + rr + 16 * i) * 1024 + o0 + cc);
                *(float4*)&tile[rr + 16 * i][cc] = v;
            }
            __syncthreads();
            const int oo = tid >> 4, kk = (tid & 15) << 2;
            u16* out = gVT + (size_t)p * 1048576;
            #pragma unroll
            for (int i = 0; i < 4; i++) {
                __align__(8) u16 t[4];
                #pragma unroll
                for (int j = 0; j < 4; j++) t[j] = f2bf(tile[kk + j][oo + 16 * i]);
                *(uint2*)(out + (size_t)(o0 + oo + 16 * i) * 1024 + k0 + kk) = *(const uint2*)t;
            }
        } else {
            // U gather: gU[p][d][k=s*256+r] = w_s * U_sel[s][d][r]
            const float* U = (p == 0) ? qU : (p == 1) ? kU : vU;
            const int d0 = bx * 64, k0 = by * 64;
            const int s = k0 >> 8, r0 = k0 & 255;
            const float* Ub = U + (size_t)idx[s] * (1024 * 256);
            const float wq = wsel[s];
            u16* out = gU + (size_t)p * 1048576;
            const int rr = tid >> 4, cc = (tid & 15) << 2;
            #pragma unroll
            for (int i = 0; i < 4; i++) {
                const float4 v = *(const float4*)(Ub + (size_t)(d0 + rr + 16 * i) * 256 + r0 + cc);
                __align__(8) u16 t[4] = { f2bf(v.x * wq), f2bf(v.y * wq),
                                          f2bf(v.z * wq), f2bf(v.w * wq) };
                *(uint2*)(out + (size_t)(d0 + rr + 16 * i) * 1024 + k0 + cc) = *(const uint2*)t;
            }
        }
    }
}

// ---------------------------------------------------------------------------
// 64x64-tile bf16 MFMA GEMM for W_eff^T: C[m][n] = sum_k A[m,k]*B[n,k],
// M=N=K=1024, z batches slices of 1M elements. grid (16,16,4) -> 4 blocks/CU.
// ---------------------------------------------------------------------------
__global__ __launch_bounds__(256)
void mfma_gemm64(const u16* __restrict__ Asrc, const u16* __restrict__ Bsrc,
                 u16* __restrict__ Cout)
{
    __shared__ u16 As[64 * 64];
    __shared__ u16 Bs[64 * 64];
    const int z = blockIdx.z;
    const u16* A = Asrc + (size_t)z * 1048576;
    const u16* B = Bsrc + (size_t)z * 1048576;
    u16* C = Cout + (size_t)z * 1048576;
    const int tid = threadIdx.x, lane = tid & 63, wave = tid >> 6;
    const int m0 = blockIdx.y * 64, n0 = blockIdx.x * 64;
    const int wn = wave * 16;

    f32x4 acc[4];
    #pragma unroll
    for (int i = 0; i < 4; i++) acc[i] = (f32x4)0.f;

    for (int k0 = 0; k0 < 1024; k0 += 64) {
        __syncthreads();
        #pragma unroll
        for (int it = 0; it < 2; it++) {
            const int c   = it * 256 + tid;
            const int row = c >> 3, j = c & 7;
            const int g   = j ^ (row & 7);
            const u16* ga = A + (size_t)(m0 + row) * 1024 + k0 + g * 8;
            __builtin_amdgcn_global_load_lds(
                (const __attribute__((address_space(1))) u32*)ga,
                (__attribute__((address_space(3))) u32*)&As[(it * 256 + wave * 64) * 8],
                16, 0, 0);
            const u16* gb = B + (size_t)(n0 + row) * 1024 + k0 + g * 8;
            __builtin_amdgcn_global_load_lds(
                (const __attribute__((address_space(1))) u32*)gb,
                (__attribute__((address_space(3))) u32*)&Bs[(it * 256 + wave * 64) * 8],
                16, 0, 0);
        }
        __syncthreads();
        #pragma unroll
        for (int ks = 0; ks < 2; ks++) {
            const int gk = ks * 4 + (lane >> 4);
            const int rn = wn + (lane & 15);
            const int jb = gk ^ (rn & 7);
            const bf16x8 bfr = *(const bf16x8*)&Bs[rn * 64 + jb * 8];
            #pragma unroll
            for (int mi = 0; mi < 4; mi++) {
                const int rm = mi * 16 + (lane & 15);
                const int ja = gk ^ (rm & 7);
                const bf16x8 af = *(const bf16x8*)&As[rm * 64 + ja * 8];
                acc[mi] = __builtin_amdgcn_mfma_f32_16x16x32_bf16(af, bfr, acc[mi], 0, 0, 0);
            }
        }
    }
    const int col_l = lane & 15, row_l = (lane >> 4) * 4;
    #pragma unroll
    for (int mi = 0; mi < 4; mi++)
        #pragma unroll
        for (int i = 0; i < 4; i++)
            C[(size_t)(m0 + mi * 16 + row_l + i) * 1024 + n0 + wn + col_l] = f2bf(acc[mi][i]);
}

// ---------------------------------------------------------------------------
// 128x128-tile bf16 MFMA GEMM, M=8192, N=K=1024, z-batched. XCD-swizzled
// block decode (flat%8 = XCD under round-robin) pins an 8-row m-group per
// XCD: per-z working set A 2MB + B 2MB fits the 4MB XCD L2.
// REQUIRES grid == (8, 64, Z).
// ---------------------------------------------------------------------------
template<int OUTBF>
__global__ __launch_bounds__(256)
void mfma_gemm(const u16* __restrict__ Asrc, const u16* __restrict__ Bt,
               void* __restrict__ Cout, size_t astride, size_t bstride, size_t cstride)
{
    __shared__ u16 As[128 * 64];
    __shared__ u16 Bs[128 * 64];
    const int flat = blockIdx.x + 8 * (blockIdx.y + 64 * blockIdx.z);
    const int xcd = flat & 7;
    const int r   = flat >> 3;
    const int nb = r & 7, mlocal = (r >> 3) & 7, zb = r >> 6;
    const int m0 = (xcd * 8 + mlocal) * 128, n0 = nb * 128;

    const u16* A = Asrc + (size_t)zb * astride;
    const u16* B = Bt   + (size_t)zb * bstride;
    const int tid  = threadIdx.x;
    const int lane = tid & 63, wave = tid >> 6;
    const int wm = (wave >> 1) * 64, wn = (wave & 1) * 64;

    f32x4 acc[4][4];
    #pragma unroll
    for (int i = 0; i < 4; i++)
        #pragma unroll
        for (int j = 0; j < 4; j++) acc[i][j] = (f32x4)0.f;

    for (int k0 = 0; k0 < 1024; k0 += 64) {
        __syncthreads();
        #pragma unroll
        for (int it = 0; it < 4; it++) {
            const int c   = it * 256 + tid;
            const int row = c >> 3, j = c & 7;
            const int g   = j ^ (row & 7);
            const u16* ga = A + (size_t)(m0 + row) * 1024 + k0 + g * 8;
            __builtin_amdgcn_global_load_lds(
                (const __attribute__((address_space(1))) u32*)ga,
                (__attribute__((address_space(3))) u32*)&As[(it * 256 + wave * 64) * 8],
                16, 0, 0);
            const u16* gb = B + (size_t)(n0 + row) * 1024 + k0 + g * 8;
            __builtin_amdgcn_global_load_lds(
                (const __attribute__((address_space(1))) u32*)gb,
                (__attribute__((address_space(3))) u32*)&Bs[(it * 256 + wave * 64) * 8],
                16, 0, 0);
        }
        __syncthreads();
        #pragma unroll
        for (int ks = 0; ks < 2; ks++) {
            bf16x8 af[4], bfr[4];
            const int gk = ks * 4 + (lane >> 4);
            #pragma unroll
            for (int mi = 0; mi < 4; mi++) {
                const int rr  = wm + mi * 16 + (lane & 15);
                const int ja = gk ^ (rr & 7);
                af[mi] = *(const bf16x8*)&As[rr * 64 + ja * 8];
                const int rn = wn + mi * 16 + (lane & 15);
                const int jb = gk ^ (rn & 7);
                bfr[mi] = *(const bf16x8*)&Bs[rn * 64 + jb * 8];
            }
            #pragma unroll
            for (int mi = 0; mi < 4; mi++)
                #pragma unroll
                for (int ni = 0; ni < 4; ni++)
                    acc[mi][ni] = __builtin_amdgcn_mfma_f32_16x16x32_bf16(
                        af[mi], bfr[ni], acc[mi][ni], 0, 0, 0);
        }
    }
    // epilogue: C/D layout col=lane&15, row=(lane>>4)*4+reg  [m89-verified]
    const int col_l = lane & 15, row_l = (lane >> 4) * 4;
    if (OUTBF) {
        u16* C = (u16*)Cout + (size_t)zb * cstride;
        #pragma unroll
        for (int mi = 0; mi < 4; mi++)
            #pragma unroll
            for (int ni = 0; ni < 4; ni++)
                #pragma unroll
                for (int i = 0; i < 4; i++) {
                    const int rw  = m0 + wm + mi * 16 + row_l + i;
                    const int cn = n0 + wn + ni * 16 + col_l;
                    C[(size_t)rw * 1024 + cn] = f2bf(acc[mi][ni][i]);
                }
    } else {
        float* C = (float*)Cout + (size_t)zb * cstride;
        #pragma unroll
        for (int mi = 0; mi < 4; mi++)
            #pragma unroll
            for (int ni = 0; ni < 4; ni++)
                #pragma unroll
                for (int i = 0; i < 4; i++) {
                    const int rw  = m0 + wm + mi * 16 + row_l + i;
                    const int cn = n0 + wn + ni * 16 + col_l;
                    C[(size_t)rw * 1024 + cn] = acc[mi][ni][i];
                }
    }
}

// ---------------------------------------------------------------------------
// Chunk-parallel scan, CT=32, NC=64. s_t = a_t*s_{t-1} + sigmoid(g)*k*v.
// 256-thread blocks = 4 independent wave-units (no intra-block sync needed).
// scan1: local scan per chunk; writes rounded kv product (kvb), chunk-local
// state Lc[ci][d] and decay product Pc[ci].
// ---------------------------------------------------------------------------
__global__ __launch_bounds__(256)
void scan1(const u16* __restrict__ Kq, const u16* __restrict__ Vq, const u16* __restrict__ Gq,
           const float* __restrict__ dec, u16* __restrict__ kvb,
           float* __restrict__ Lc, float* __restrict__ Pc)
{
    const int unit = blockIdx.x * 4 + (threadIdx.x >> 6);   // 0..4095
    const int d = threadIdx.x & 63;
    const int c = unit & (NC - 1), h = (unit >> 6) & 15, b = unit >> 10;
    const size_t t0 = (size_t)b * SEQ + c * CT;
    const size_t base = t0 * 1024 + h * 64 + d;
    const u16* kp = Kq + base;
    const u16* vp = Vq + base;
    const u16* gp = Gq + base;
    const float* dp = dec + t0 * 16 + h;
    float s = 0.f, P = 1.f;
    #pragma unroll 4
    for (int t = 0; t < CT; t++) {
        const size_t o = (size_t)t * 1024;
        const float a  = dp[t * 16];
        const u16 kq = f2bf(b2f(kp[o]) * b2f(vp[o]) * sigf(b2f(gp[o])));
        kvb[base + o] = kq;
        s = fmaf(a, s, b2f(kq));
        P *= a;
    }
    const int ci = (b * 16 + h) * NC + c;
    Lc[(size_t)ci * 64 + d] = s;
    if (d == 0) Pc[ci] = P;
}

// scan2 folded into scan3: each unit combines its chunk prefix inline.
__global__ __launch_bounds__(256)
void scan3(const u16* __restrict__ Qq, const u16* __restrict__ kvb,
           const float* __restrict__ dec,
           const float* __restrict__ Lc, const float* __restrict__ Pc,
           u16* __restrict__ attb)
{
    const int unit = blockIdx.x * 4 + (threadIdx.x >> 6);
    const int d = threadIdx.x & 63;
    const int c = unit & (NC - 1), h = (unit >> 6) & 15, b = unit >> 10;
    const size_t t0 = (size_t)b * SEQ + c * CT;
    const size_t base = t0 * 1024 + h * 64 + d;
    const u16* qp = Qq + base;
    const u16* kp = kvb + base;
    const float* dp = dec + t0 * 16 + h;

    // inline prefix combine over earlier chunks of this (b,h)
    const int ci0 = (b * 16 + h) * NC;
    float s = 0.f;
    for (int cc = 0; cc < c; cc++)
        s = fmaf(Pc[ci0 + cc], s, Lc[(size_t)(ci0 + cc) * 64 + d]);

    #pragma unroll 4
    for (int t = 0; t < CT; t++) {
        const size_t o = (size_t)t * 1024;
        const float a  = dp[t * 16];
        s = fmaf(a, s, b2f(kp[o]));
        attb[base + o] = f2bf(b2f(qp[o]) * s);
    }
}

// ---------------------------------------------------------------------------
// RMSNorm * rms_w * sigmoid(gpre) -> bf16. One wave per token (4 tokens per
// block), butterfly-only reduction, no LDS/syncthreads.
// ---------------------------------------------------------------------------
__global__ __launch_bounds__(256)
void rms_gate(const u16* __restrict__ attb, const u16* __restrict__ gpre,
              const float* __restrict__ rmsw, u16* __restrict__ o)
{
    const int wave = threadIdx.x >> 6, lane = threadIdx.x & 63;
    const size_t t = (size_t)blockIdx.x * 4 + wave;
    const ushort4* ap = (const ushort4*)(attb + t * 1024);
    ushort4 a4[4];
    float ss = 0.f;
    #pragma unroll
    for (int i = 0; i < 4; i++) {
        a4[i] = ap[lane + 64 * i];
        const float ax = b2f(a4[i].x), ay = b2f(a4[i].y);
        const float az = b2f(a4[i].z), aw = b2f(a4[i].w);
        ss += ax*ax + ay*ay + az*az + aw*aw;
    }
    #pragma unroll
    for (int off = 32; off > 0; off >>= 1) ss += __shfl_xor(ss, off);
    const float scale = rsqrtf(ss * (1.0f / 1024.0f) + 1.1920929e-7f);
    const ushort4* gp = (const ushort4*)(gpre + t * 1024);
    const float4*  wp = (const float4*)rmsw;
    uint2* op = (uint2*)(o + t * 1024);
    #pragma unroll
    for (int i = 0; i < 4; i++) {
        const ushort4 g4 = gp[lane + 64 * i];
        const float4  w  = wp[lane + 64 * i];
        __align__(8) u16 r[4];
        r[0] = f2bf(b2f(a4[i].x) * scale * w.x * sigf(b2f(g4.x)));
        r[1] = f2bf(b2f(a4[i].y) * scale * w.y * sigf(b2f(g4.y)));
        r[2] = f2bf(b2f(a4[i].z) * scale * w.z * sigf(b2f(g4.z)));
        r[3] = f2bf(b2f(a4[i].w) * scale * w.w * sigf(b2f(g4.w)));
        op[lane + 64 * i] = *(const uint2*)r;
    }
}

// ---------------------------------------------------------------------------
extern "C" void kernel_launch(void* const* d_in, const int* in_sizes, int n_in,
                              void* d_out, int out_size, void* d_ws, size_t ws_size,
                              hipStream_t stream)
{
    const float* x    = (const float*)d_in[0];
    const float* qU   = (const float*)d_in[1];
    const float* qV   = (const float*)d_in[2];
    const float* kU   = (const float*)d_in[3];
    const float* kV   = (const float*)d_in[4];
    const float* vU   = (const float*)d_in[5];
    const float* vV   = (const float*)d_in[6];
    const float* ql   = (const float*)d_in[7];
    const float* kl   = (const float*)d_in[8];
    const float* vl   = (const float*)d_in[9];
    const float* gl   = (const float*)d_in[10];
    const float* dw   = (const float*)d_in[11];
    const float* db   = (const float*)d_in[12];
    const float* ogw  = (const float*)d_in[13];
    const float* opw  = (const float*)d_in[14];
    const float* rmsw = (const float*)d_in[15];

    // workspace layout (byte offsets, ~165.2 MB total)
    char* w = (char*)d_ws;
    float* dec  = (float*)(w + 0);           // 512 KB
    u16*   WT   = (u16*)  (w + 524288);      // 5 slices x 2 MB (slice4 = ogwb)
    u16*   xb   = (u16*)  (w + 11010048);    // 16 MB
    u16*   opwb = (u16*)  (w + 27787264);    // 2 MB
    u16*   QKVG = (u16*)  (w + 29884416);    // 5 slices x 16 MB (q,k,v,g,gpre)
    u16*   RMSO = (u16*)  (w + 113770496);   // 16 MB
    u16*   ATTb = (u16*)  (w + 130547712);   // 16 MB
    u16*   kvb  = (u16*)  (w + 147324928);   // 16 MB
    float* Lc   = (float*)(w + 164102144);   // 1 MB
    float* Pc   = (float*)(w + 165150720);   // 16 KB
    // gU/gVT alias the QKVG region (consumed by weff-gemm before QKVG written)
    u16*   gU   = QKVG;                      // 8 MB
    u16*   gVT  = QKVG + 4194304;            // 8 MB
    u16*   ogwb = WT + 4 * 1048576;          // WT slice 4
    u16*   GPRE = QKVG + 4 * 8388608;        // QKVG slice 4

    // 1. prep: x cast + decay fused (x row in regs), weight casts, gathers
    prep<<<6144, 256, 0, stream>>>(x, ogw, opw, qU, kU, vU, qV, kV, vV,
                                   ql, kl, vl, gl, dw, db,
                                   xb, ogwb, opwb, gU, gVT, dec);

    // 2. WT[p][o][d] = sum_k gVT[p][o,k] * gU[p][d,k]  (= W_eff^T)
    mfma_gemm64<<<dim3(16, 16, 4), 256, 0, stream>>>(gVT, gU, WT);

    // 3. q,k,v,gate,gpre = x @ {W_eff_p, out_gate_w}^T -> bf16, z=5 batch
    mfma_gemm<1><<<dim3(8, 64, 5), 256, 0, stream>>>(xb, WT, QKVG,
                                                     (size_t)0, (size_t)1048576,
                                                     (size_t)8388608);

    // 4-5. chunk-parallel scan (prefix combine inlined in scan3)
    scan1<<<1024, 256, 0, stream>>>(QKVG + 8388608, QKVG + 16777216, QKVG + 25165824,
                                    dec, kvb, Lc, Pc);
    scan3<<<1024, 256, 0, stream>>>(QKVG, kvb, dec, Lc, Pc, ATTb);

    // 6. rmsnorm * gate
    rms_gate<<<2048, 256, 0, stream>>>(ATTb, GPRE, rmsw, RMSO);

    // 7. final: rmso @ out_proj_w^T -> fp32 d_out
    mfma_gemm<0><<<dim3(8, 64, 1), 256, 0, stream>>>(RMSO, opwb, (float*)d_out, 0, 0, 0);
}

// Round 9
// 389.788 us; speedup vs baseline: 3.3516x; 1.0108x over previous
//
#include <hip/hip_runtime.h>
#include <hip/hip_bf16.h>

// Problem constants (B=4, S=2048, D_MODEL=1024, H=16, DH=64, RANK=256, NPRIM=16, top_k=4)
#define TOK 8192
#define SEQ 2048
#define CT  32          // scan chunk length
#define NC  64          // chunks per sequence

typedef __attribute__((ext_vector_type(8))) short bf16x8;   // 8 bf16 = 4 VGPRs
typedef __attribute__((ext_vector_type(4))) float f32x4;
typedef unsigned short u16;
typedef unsigned int   u32;

__device__ __forceinline__ u16 f2bf(float f) {
    u32 u = __float_as_uint(f);
    u = (u + 0x7FFFu + ((u >> 16) & 1u)) >> 16;   // RNE
    return (u16)u;
}
__device__ __forceinline__ float b2f(u16 h) { return __uint_as_float(((u32)h) << 16); }
__device__ __forceinline__ float sigf(float z) { return 1.f / (1.f + __expf(-z)); }

// Top-4 of 16 logits + softmax over the kept 4 (== softmax->topk->renorm, exact).
__device__ __forceinline__ void topk4(const float* __restrict__ lg, int* idx, float* wv)
{
    float v[16];
    #pragma unroll
    for (int i = 0; i < 16; i++) v[i] = lg[i];
    bool used[16];
    #pragma unroll
    for (int i = 0; i < 16; i++) used[i] = false;
    float val[4];
    #pragma unroll
    for (int k = 0; k < 4; k++) {
        int bi = 0; float bv = -3.0e38f;
        #pragma unroll
        for (int i = 0; i < 16; i++)
            if (!used[i] && v[i] > bv) { bv = v[i]; bi = i; }
        used[bi] = true; idx[k] = bi; val[k] = bv;
    }
    float e[4], s = 0.f;
    #pragma unroll
    for (int k = 0; k < 4; k++) { e[k] = expf(val[k] - val[0]); s += e[k]; }
    #pragma unroll
    for (int k = 0; k < 4; k++) wv[k] = e[k] / s;
}

// ---------------------------------------------------------------------------
// prep: one dispatch, branch by block range.
//   [0, 2048)    : x cast -> bf16 AND decay dec[t][h] (x row held in regs)
//   [2048, 3072) : out_gate_w cast
//   [3072, 4096) : out_proj_w cast
//   [4096, 6144) : gather selected prims -> gU (w folded), gVT (transposed)
// ---------------------------------------------------------------------------
__global__ __launch_bounds__(256)
void prep(const float* __restrict__ x, const float* __restrict__ ogw,
          const float* __restrict__ opw,
          const float* __restrict__ qU, const float* __restrict__ kU,
          const float* __restrict__ vU,
          const float* __restrict__ qV, const float* __restrict__ kV,
          const float* __restrict__ vV,
          const float* __restrict__ ql, const float* __restrict__ kl,
          const float* __restrict__ vl, const float* __restrict__ gl,
          const float* __restrict__ dw, const float* __restrict__ db,
          u16* __restrict__ xb, u16* __restrict__ ogwb, u16* __restrict__ opwb,
          u16* __restrict__ gU, u16* __restrict__ gVT, float* __restrict__ dec)
{
    const int blk = blockIdx.x;
    const int tid = threadIdx.x;

    if (blk < 2048) {
        // ---- x cast + decay: one wave per token ----
        const int wave = tid >> 6, lane = tid & 63;
        const int t = blk * 4 + wave;
        const float4* x4 = (const float4*)(x + (size_t)t * 1024);
        float4 xv[4];
        #pragma unroll
        for (int i = 0; i < 4; i++) xv[i] = x4[lane + 64 * i];
        // cast-store the row
        uint2* xrow = (uint2*)(xb + (size_t)t * 1024);
        #pragma unroll
        for (int i = 0; i < 4; i++) {
            __align__(8) u16 tq[4] = { f2bf(xv[i].x), f2bf(xv[i].y),
                                       f2bf(xv[i].z), f2bf(xv[i].w) };
            xrow[lane + 64 * i] = *(const uint2*)tq;
        }
        // 16 head dots from the same registers
        float p[16];
        #pragma unroll
        for (int h = 0; h < 16; h++) {
            const float4* w4 = (const float4*)(dw + (size_t)h * 1024);
            float s = 0.f;
            #pragma unroll
            for (int i = 0; i < 4; i++) {
                const float4 wv = w4[lane + 64 * i];
                s = fmaf(xv[i].x, wv.x, fmaf(xv[i].y, wv.y,
                    fmaf(xv[i].z, wv.z, fmaf(xv[i].w, wv.w, s))));
            }
            p[h] = s;
        }
        #pragma unroll
        for (int off = 32; off > 0; off >>= 1)
            #pragma unroll
            for (int h = 0; h < 16; h++) p[h] += __shfl_xor(p[h], off);
        if (lane == 0) {
            #pragma unroll
            for (int h = 0; h < 16; h++)
                dec[(size_t)t * 16 + h] = 1.f / (1.f + __expf(p[h] + db[h]));
        }
        return;
    }
    if (blk < 4096) {
        // ---- weight casts: 1 float4 per thread ----
        const float* src; u16* dst;
        int off;
        if (blk < 3072) { src = ogw; dst = ogwb; off = (blk - 2048) * 256 + tid; }
        else            { src = opw; dst = opwb; off = (blk - 3072) * 256 + tid; }
        const float4 v = ((const float4*)src)[off];
        __align__(8) u16 t[4] = { f2bf(v.x), f2bf(v.y), f2bf(v.z), f2bf(v.w) };
        ((uint2*)dst)[off] = *(const uint2*)t;
        return;
    }
    // ---- gather (topk inline, exact) ----
    {
        const int local = blk - 4096;
        const int z = local >> 8;              // 0..7
        const int bx = local & 15, by = (local >> 4) & 15;
        const int p = z & 3;
        const float* lg = (p == 0) ? ql : (p == 1) ? kl : (p == 2) ? vl : gl;
        int idx[4]; float wsel[4];
        topk4(lg, idx, wsel);

        if (z < 4) {
            // V^T gather: gVT[p][o][k=s*256+r] = V_sel[s][r][o]
            const float* V = (p == 0) ? qV : (p == 1) ? kV : vV;
            const int o0 = bx * 64, k0 = by * 64;
            const int s = k0 >> 8, r0 = k0 & 255;
            const float* Vb = V + (size_t)idx[s] * (256 * 1024);
            __shared__ float tile[64][68];
            const int rr = tid >> 4, cc = (tid & 15) << 2;
            #pragma unroll
            for (int i = 0; i < 4; i++) {
                const float4 v = *(const float4*)(Vb + (size_t)(r0 + rr + 16 * i) * 1024 + o0 + cc);
                *(float4*)&tile[rr + 16 * i][cc] = v;
            }
            __syncthreads();
            const int oo = tid >> 4, kk = (tid & 15) << 2;
            u16* out = gVT + (size_t)p * 1048576;
            #pragma unroll
            for (int i = 0; i < 4; i++) {
                __align__(8) u16 t[4];
                #pragma unroll
                for (int j = 0; j < 4; j++) t[j] = f2bf(tile[kk + j][oo + 16 * i]);
                *(uint2*)(out + (size_t)(o0 + oo + 16 * i) * 1024 + k0 + kk) = *(const uint2*)t;
            }
        } else {
            // U gather: gU[p][d][k=s*256+r] = w_s * U_sel[s][d][r]
            const float* U = (p == 0) ? qU : (p == 1) ? kU : vU;
            const int d0 = bx * 64, k0 = by * 64;
            const int s = k0 >> 8, r0 = k0 & 255;
            const float* Ub = U + (size_t)idx[s] * (1024 * 256);
            const float wq = wsel[s];
            u16* out = gU + (size_t)p * 1048576;
            const int rr = tid >> 4, cc = (tid & 15) << 2;
            #pragma unroll
            for (int i = 0; i < 4; i++) {
                const float4 v = *(const float4*)(Ub + (size_t)(d0 + rr + 16 * i) * 256 + r0 + cc);
                __align__(8) u16 t[4] = { f2bf(v.x * wq), f2bf(v.y * wq),
                                          f2bf(v.z * wq), f2bf(v.w * wq) };
                *(uint2*)(out + (size_t)(d0 + rr + 16 * i) * 1024 + k0 + cc) = *(const uint2*)t;
            }
        }
    }
}

// ---------------------------------------------------------------------------
// 64x64-tile bf16 MFMA GEMM for W_eff^T: C[m][n] = sum_k A[m,k]*B[n,k],
// M=N=K=1024, z batches slices of 1M elements. grid (16,16,4) -> 4 blocks/CU.
// ---------------------------------------------------------------------------
__global__ __launch_bounds__(256)
void mfma_gemm64(const u16* __restrict__ Asrc, const u16* __restrict__ Bsrc,
                 u16* __restrict__ Cout)
{
    __shared__ u16 As[64 * 64];
    __shared__ u16 Bs[64 * 64];
    const int z = blockIdx.z;
    const u16* A = Asrc + (size_t)z * 1048576;
    const u16* B = Bsrc + (size_t)z * 1048576;
    u16* C = Cout + (size_t)z * 1048576;
    const int tid = threadIdx.x, lane = tid & 63, wave = tid >> 6;
    const int m0 = blockIdx.y * 64, n0 = blockIdx.x * 64;
    const int wn = wave * 16;

    f32x4 acc[4];
    #pragma unroll
    for (int i = 0; i < 4; i++) acc[i] = (f32x4)0.f;

    for (int k0 = 0; k0 < 1024; k0 += 64) {
        __syncthreads();
        #pragma unroll
        for (int it = 0; it < 2; it++) {
            const int c   = it * 256 + tid;
            const int row = c >> 3, j = c & 7;
            const int g   = j ^ (row & 7);
            const u16* ga = A + (size_t)(m0 + row) * 1024 + k0 + g * 8;
            __builtin_amdgcn_global_load_lds(
                (const __attribute__((address_space(1))) u32*)ga,
                (__attribute__((address_space(3))) u32*)&As[(it * 256 + wave * 64) * 8],
                16, 0, 0);
            const u16* gb = B + (size_t)(n0 + row) * 1024 + k0 + g * 8;
            __builtin_amdgcn_global_load_lds(
                (const __attribute__((address_space(1))) u32*)gb,
                (__attribute__((address_space(3))) u32*)&Bs[(it * 256 + wave * 64) * 8],
                16, 0, 0);
        }
        __syncthreads();
        #pragma unroll
        for (int ks = 0; ks < 2; ks++) {
            const int gk = ks * 4 + (lane >> 4);
            const int rn = wn + (lane & 15);
            const int jb = gk ^ (rn & 7);
            const bf16x8 bfr = *(const bf16x8*)&Bs[rn * 64 + jb * 8];
            #pragma unroll
            for (int mi = 0; mi < 4; mi++) {
                const int rm = mi * 16 + (lane & 15);
                const int ja = gk ^ (rm & 7);
                const bf16x8 af = *(const bf16x8*)&As[rm * 64 + ja * 8];
                acc[mi] = __builtin_amdgcn_mfma_f32_16x16x32_bf16(af, bfr, acc[mi], 0, 0, 0);
            }
        }
    }
    const int col_l = lane & 15, row_l = (lane >> 4) * 4;
    #pragma unroll
    for (int mi = 0; mi < 4; mi++)
        #pragma unroll
        for (int i = 0; i < 4; i++)
            C[(size_t)(m0 + mi * 16 + row_l + i) * 1024 + n0 + wn + col_l] = f2bf(acc[mi][i]);
}

// ---------------------------------------------------------------------------
// 128x128-tile bf16 MFMA GEMM, M=8192, N=K=1024, z-batched. XCD-swizzled
// block decode (flat%8 = XCD under round-robin) pins an 8-row m-group per
// XCD: per-z working set A 2MB + B 2MB fits the 4MB XCD L2.
// REQUIRES grid == (8, 64, Z).
// ---------------------------------------------------------------------------
template<int OUTBF>
__global__ __launch_bounds__(256)
void mfma_gemm(const u16* __restrict__ Asrc, const u16* __restrict__ Bt,
               void* __restrict__ Cout, size_t astride, size_t bstride, size_t cstride)
{
    __shared__ u16 As[128 * 64];
    __shared__ u16 Bs[128 * 64];
    const int flat = blockIdx.x + 8 * (blockIdx.y + 64 * blockIdx.z);
    const int xcd = flat & 7;
    const int r   = flat >> 3;
    const int nb = r & 7, mlocal = (r >> 3) & 7, zb = r >> 6;
    const int m0 = (xcd * 8 + mlocal) * 128, n0 = nb * 128;

    const u16* A = Asrc + (size_t)zb * astride;
    const u16* B = Bt   + (size_t)zb * bstride;
    const int tid  = threadIdx.x;
    const int lane = tid & 63, wave = tid >> 6;
    const int wm = (wave >> 1) * 64, wn = (wave & 1) * 64;

    f32x4 acc[4][4];
    #pragma unroll
    for (int i = 0; i < 4; i++)
        #pragma unroll
        for (int j = 0; j < 4; j++) acc[i][j] = (f32x4)0.f;

    for (int k0 = 0; k0 < 1024; k0 += 64) {
        __syncthreads();
        #pragma unroll
        for (int it = 0; it < 4; it++) {
            const int c   = it * 256 + tid;
            const int row = c >> 3, j = c & 7;
            const int g   = j ^ (row & 7);
            const u16* ga = A + (size_t)(m0 + row) * 1024 + k0 + g * 8;
            __builtin_amdgcn_global_load_lds(
                (const __attribute__((address_space(1))) u32*)ga,
                (__attribute__((address_space(3))) u32*)&As[(it * 256 + wave * 64) * 8],
                16, 0, 0);
            const u16* gb = B + (size_t)(n0 + row) * 1024 + k0 + g * 8;
            __builtin_amdgcn_global_load_lds(
                (const __attribute__((address_space(1))) u32*)gb,
                (__attribute__((address_space(3))) u32*)&Bs[(it * 256 + wave * 64) * 8],
                16, 0, 0);
        }
        __syncthreads();
        #pragma unroll
        for (int ks = 0; ks < 2; ks++) {
            bf16x8 af[4], bfr[4];
            const int gk = ks * 4 + (lane >> 4);
            #pragma unroll
            for (int mi = 0; mi < 4; mi++) {
                const int rr  = wm + mi * 16 + (lane & 15);
                const int ja = gk ^ (rr & 7);
                af[mi] = *(const bf16x8*)&As[rr * 64 + ja * 8];
                const int rn = wn + mi * 16 + (lane & 15);
                const int jb = gk ^ (rn & 7);
                bfr[mi] = *(const bf16x8*)&Bs[rn * 64 + jb * 8];
            }
            #pragma unroll
            for (int mi = 0; mi < 4; mi++)
                #pragma unroll
                for (int ni = 0; ni < 4; ni++)
                    acc[mi][ni] = __builtin_amdgcn_mfma_f32_16x16x32_bf16(
                        af[mi], bfr[ni], acc[mi][ni], 0, 0, 0);
        }
    }
    // epilogue: C/D layout col=lane&15, row=(lane>>4)*4+reg  [m89-verified]
    const int col_l = lane & 15, row_l = (lane >> 4) * 4;
    if (OUTBF) {
        u16* C = (u16*)Cout + (size_t)zb * cstride;
        #pragma unroll
        for (int mi = 0; mi < 4; mi++)
            #pragma unroll
            for (int ni = 0; ni < 4; ni++)
                #pragma unroll
                for (int i = 0; i < 4; i++) {
                    const int rw  = m0 + wm + mi * 16 + row_l + i;
                    const int cn = n0 + wn + ni * 16 + col_l;
                    C[(size_t)rw * 1024 + cn] = f2bf(acc[mi][ni][i]);
                }
    } else {
        float* C = (float*)Cout + (size_t)zb * cstride;
        #pragma unroll
        for (int mi = 0; mi < 4; mi++)
            #pragma unroll
            for (int ni = 0; ni < 4; ni++)
                #pragma unroll
                for (int i = 0; i < 4; i++) {
                    const int rw  = m0 + wm + mi * 16 + row_l + i;
                    const int cn = n0 + wn + ni * 16 + col_l;
                    C[(size_t)rw * 1024 + cn] = acc[mi][ni][i];
                }
    }
}

// ---------------------------------------------------------------------------
// Chunk-parallel scan, CT=32, NC=64. s_t = a_t*s_{t-1} + sigmoid(g)*k*v.
// 256-thread blocks = 4 independent wave-units (no intra-block sync needed).
// scan1: local scan per chunk; writes rounded kv product (kvb), chunk-local
// state Lc[ci][d] and decay product Pc[ci].
// ---------------------------------------------------------------------------
__global__ __launch_bounds__(256)
void scan1(const u16* __restrict__ Kq, const u16* __restrict__ Vq, const u16* __restrict__ Gq,
           const float* __restrict__ dec, u16* __restrict__ kvb,
           float* __restrict__ Lc, float* __restrict__ Pc)
{
    const int unit = blockIdx.x * 4 + (threadIdx.x >> 6);   // 0..4095
    const int d = threadIdx.x & 63;
    const int c = unit & (NC - 1), h = (unit >> 6) & 15, b = unit >> 10;
    const size_t t0 = (size_t)b * SEQ + c * CT;
    const size_t base = t0 * 1024 + h * 64 + d;
    const u16* kp = Kq + base;
    const u16* vp = Vq + base;
    const u16* gp = Gq + base;
    const float* dp = dec + t0 * 16 + h;
    float s = 0.f, P = 1.f;
    #pragma unroll 4
    for (int t = 0; t < CT; t++) {
        const size_t o = (size_t)t * 1024;
        const float a  = dp[t * 16];
        const u16 kq = f2bf(b2f(kp[o]) * b2f(vp[o]) * sigf(b2f(gp[o])));
        kvb[base + o] = kq;
        s = fmaf(a, s, b2f(kq));
        P *= a;
    }
    const int ci = (b * 16 + h) * NC + c;
    Lc[(size_t)ci * 64 + d] = s;
    if (d == 0) Pc[ci] = P;
}

// scan2 folded into scan3: each unit combines its chunk prefix inline.
__global__ __launch_bounds__(256)
void scan3(const u16* __restrict__ Qq, const u16* __restrict__ kvb,
           const float* __restrict__ dec,
           const float* __restrict__ Lc, const float* __restrict__ Pc,
           u16* __restrict__ attb)
{
    const int unit = blockIdx.x * 4 + (threadIdx.x >> 6);
    const int d = threadIdx.x & 63;
    const int c = unit & (NC - 1), h = (unit >> 6) & 15, b = unit >> 10;
    const size_t t0 = (size_t)b * SEQ + c * CT;
    const size_t base = t0 * 1024 + h * 64 + d;
    const u16* qp = Qq + base;
    const u16* kp = kvb + base;
    const float* dp = dec + t0 * 16 + h;

    // inline prefix combine over earlier chunks of this (b,h)
    const int ci0 = (b * 16 + h) * NC;
    float s = 0.f;
    for (int cc = 0; cc < c; cc++)
        s = fmaf(Pc[ci0 + cc], s, Lc[(size_t)(ci0 + cc) * 64 + d]);

    #pragma unroll 4
    for (int t = 0; t < CT; t++) {
        const size_t o = (size_t)t * 1024;
        const float a  = dp[t * 16];
        s = fmaf(a, s, b2f(kp[o]));
        attb[base + o] = f2bf(b2f(qp[o]) * s);
    }
}

// ---------------------------------------------------------------------------
// RMSNorm * rms_w * sigmoid(gpre) -> bf16. One wave per token (4 tokens per
// block), butterfly-only reduction, no LDS/syncthreads.
// ---------------------------------------------------------------------------
__global__ __launch_bounds__(256)
void rms_gate(const u16* __restrict__ attb, const u16* __restrict__ gpre,
              const float* __restrict__ rmsw, u16* __restrict__ o)
{
    const int wave = threadIdx.x >> 6, lane = threadIdx.x & 63;
    const size_t t = (size_t)blockIdx.x * 4 + wave;
    const ushort4* ap = (const ushort4*)(attb + t * 1024);
    ushort4 a4[4];
    float ss = 0.f;
    #pragma unroll
    for (int i = 0; i < 4; i++) {
        a4[i] = ap[lane + 64 * i];
        const float ax = b2f(a4[i].x), ay = b2f(a4[i].y);
        const float az = b2f(a4[i].z), aw = b2f(a4[i].w);
        ss += ax*ax + ay*ay + az*az + aw*aw;
    }
    #pragma unroll
    for (int off = 32; off > 0; off >>= 1) ss += __shfl_xor(ss, off);
    const float scale = rsqrtf(ss * (1.0f / 1024.0f) + 1.1920929e-7f);
    const ushort4* gp = (const ushort4*)(gpre + t * 1024);
    const float4*  wp = (const float4*)rmsw;
    uint2* op = (uint2*)(o + t * 1024);
    #pragma unroll
    for (int i = 0; i < 4; i++) {
        const ushort4 g4 = gp[lane + 64 * i];
        const float4  w  = wp[lane + 64 * i];
        __align__(8) u16 r[4];
        r[0] = f2bf(b2f(a4[i].x) * scale * w.x * sigf(b2f(g4.x)));
        r[1] = f2bf(b2f(a4[i].y) * scale * w.y * sigf(b2f(g4.y)));
        r[2] = f2bf(b2f(a4[i].z) * scale * w.z * sigf(b2f(g4.z)));
        r[3] = f2bf(b2f(a4[i].w) * scale * w.w * sigf(b2f(g4.w)));
        op[lane + 64 * i] = *(const uint2*)r;
    }
}

// ---------------------------------------------------------------------------
extern "C" void kernel_launch(void* const* d_in, const int* in_sizes, int n_in,
                              void* d_out, int out_size, void* d_ws, size_t ws_size,
                              hipStream_t stream)
{
    const float* x    = (const float*)d_in[0];
    const float* qU   = (const float*)d_in[1];
    const float* qV   = (const float*)d_in[2];
    const float* kU   = (const float*)d_in[3];
    const float* kV   = (const float*)d_in[4];
    const float* vU   = (const float*)d_in[5];
    const float* vV   = (const float*)d_in[6];
    const float* ql   = (const float*)d_in[7];
    const float* kl   = (const float*)d_in[8];
    const float* vl   = (const float*)d_in[9];
    const float* gl   = (const float*)d_in[10];
    const float* dw   = (const float*)d_in[11];
    const float* db   = (const float*)d_in[12];
    const float* ogw  = (const float*)d_in[13];
    const float* opw  = (const float*)d_in[14];
    const float* rmsw = (const float*)d_in[15];

    // workspace layout (byte offsets, ~165.2 MB total)
    char* w = (char*)d_ws;
    float* dec  = (float*)(w + 0);           // 512 KB
    u16*   WT   = (u16*)  (w + 524288);      // 5 slices x 2 MB (slice4 = ogwb)
    u16*   xb   = (u16*)  (w + 11010048);    // 16 MB
    u16*   opwb = (u16*)  (w + 27787264);    // 2 MB
    u16*   QKVG = (u16*)  (w + 29884416);    // 5 slices x 16 MB (q,k,v,g,gpre)
    u16*   RMSO = (u16*)  (w + 113770496);   // 16 MB
    u16*   ATTb = (u16*)  (w + 130547712);   // 16 MB
    u16*   kvb  = (u16*)  (w + 147324928);   // 16 MB
    float* Lc   = (float*)(w + 164102144);   // 1 MB
    float* Pc   = (float*)(w + 165150720);   // 16 KB
    // gU/gVT alias the QKVG region (consumed by weff-gemm before QKVG written)
    u16*   gU   = QKVG;                      // 8 MB
    u16*   gVT  = QKVG + 4194304;            // 8 MB
    u16*   ogwb = WT + 4 * 1048576;          // WT slice 4
    u16*   GPRE = QKVG + 4 * 8388608;        // QKVG slice 4

    // 1. prep: x cast + decay fused (x row in regs), weight casts, gathers
    prep<<<6144, 256, 0, stream>>>(x, ogw, opw, qU, kU, vU, qV, kV, vV,
                                   ql, kl, vl, gl, dw, db,
                                   xb, ogwb, opwb, gU, gVT, dec);

    // 2. WT[p][o][d] = sum_k gVT[p][o,k] * gU[p][d,k]  (= W_eff^T)
    mfma_gemm64<<<dim3(16, 16, 4), 256, 0, stream>>>(gVT, gU, WT);

    // 3. q,k,v,gate,gpre = x @ {W_eff_p, out_gate_w}^T -> bf16, z=5 batch
    mfma_gemm<1><<<dim3(8, 64, 5), 256, 0, stream>>>(xb, WT, QKVG,
                                                     (size_t)0, (size_t)1048576,
                                                     (size_t)8388608);

    // 4-5. chunk-parallel scan (prefix combine inlined in scan3)
    scan1<<<1024, 256, 0, stream>>>(QKVG + 8388608, QKVG + 16777216, QKVG + 25165824,
                                    dec, kvb, Lc, Pc);
    scan3<<<1024, 256, 0, stream>>>(QKVG, kvb, dec, Lc, Pc, ATTb);

    // 6. rmsnorm * gate
    rms_gate<<<2048, 256, 0, stream>>>(ATTb, GPRE, rmsw, RMSO);

    // 7. final: rmso @ out_proj_w^T -> fp32 d_out
    mfma_gemm<0><<<dim3(8, 64, 1), 256, 0, stream>>>(RMSO, opwb, (float*)d_out, 0, 0, 0);
}